// Round 1
// baseline (261.474 us; speedup 1.0000x reference)
//
#include <hip/hip_runtime.h>
#include <stdint.h>

#define NQ 64
#define ZNEAR 0.1f
#define ZFAR 1000.0f

// ---------------- wave reductions (64-lane) ----------------
__device__ __forceinline__ float wave_min_f(float v) {
    #pragma unroll
    for (int off = 1; off < 64; off <<= 1)
        v = fminf(v, __shfl_xor(v, off, 64));
    return v;
}
__device__ __forceinline__ float wave_max_f(float v) {
    #pragma unroll
    for (int off = 1; off < 64; off <<= 1)
        v = fmaxf(v, __shfl_xor(v, off, 64));
    return v;
}

// ---------------- K1: project points, store z + packed(x,y,valid), reduce dmin/dmax ----------------
// packed layout: bit31 = valid, bits[0:12) = x, bits[12:24) = y, bits[24:30) = depth bin (written by K2)
__global__ void k_project(const float* __restrict__ pp, const float* __restrict__ conf,
                          const float* __restrict__ pose, const float* __restrict__ Km,
                          const int* __restrict__ hp, const int* __restrict__ wp,
                          int B, int n,
                          float* __restrict__ zbuf, unsigned* __restrict__ packed,
                          unsigned* __restrict__ dmin_u, unsigned* __restrict__ dmax_u) {
    int i = blockIdx.x * blockDim.x + threadIdx.x;
    int h = *hp, w = *wp;
    for (int bb = 0; bb < B; ++bb) {
        float inv_lo = INFINITY;   // neutral for min (inactive lanes)
        float inv_hi = 0.0f;       // neutral for max
        if (i < n) {
            const float* P  = pose + (size_t)bb * 16;
            const float* km = Km   + (size_t)bb * 9;
            const float* pb = pp   + (size_t)bb * 7 * n;
            float X = pb[0 * (size_t)n + i];
            float Y = pb[1 * (size_t)n + i];
            float Z = pb[2 * (size_t)n + i];
            float Wc = pb[3 * (size_t)n + i];
            float pc0 = P[0] * X + P[1] * Y + P[2]  * Z + P[3]  * Wc;
            float pc1 = P[4] * X + P[5] * Y + P[6]  * Z + P[7]  * Wc;
            float pc2 = P[8] * X + P[9] * Y + P[10] * Z + P[11] * Wc;
            float z = fabsf(pc2);
            // mirror reference op order: (pc * f) / z + c
            float xc = pc0 * km[0] / z + km[2];
            float yc = pc1 * km[4] / z + km[5];
            float xr = rintf(xc);   // round-half-even, same as jnp.round
            float yr = rintf(yc);
            float cf = conf[(size_t)bb * n + i];
            bool valid = (xr >= 0.0f) && (xr <= (float)(w - 1)) &&
                         (yr >= 0.0f) && (yr <= (float)(h - 1)) &&
                         (z >= ZNEAR) && (z <= ZFAR) && (cf > 0.0f);
            unsigned px = valid ? (unsigned)(int)xr : 0u;
            unsigned py = valid ? (unsigned)(int)yr : 0u;
            zbuf[(size_t)bb * n + i] = z;
            packed[(size_t)bb * n + i] = (valid ? 0x80000000u : 0u) | px | (py << 12);
            // reference: 1/where(oob, 1e-10, z) and 1/where(oob, 1e10, z)
            inv_lo = valid ? (1.0f / z) : (1.0f / 1e-10f);
            inv_hi = valid ? (1.0f / z) : (1.0f / 1e10f);
        }
        float wmin = wave_min_f(inv_lo);
        float wmax = wave_max_f(inv_hi);
        if ((threadIdx.x & 63) == 0) {
            // all candidates are positive floats -> uint bit order == float order
            atomicMin(&dmin_u[bb], __float_as_uint(wmin));
            atomicMax(&dmax_u[bb], __float_as_uint(wmax));
        }
    }
}

// ---------------- K2: compute depth bin, bin winner = max point index (last-write-wins) ----------------
__global__ void k_binwin(const float* __restrict__ zbuf, unsigned* __restrict__ packed,
                         const float* __restrict__ dminb, const float* __restrict__ dmaxb,
                         const int* __restrict__ hp, const int* __restrict__ wp,
                         int B, int n, unsigned* __restrict__ winner) {
    int p = blockIdx.x * blockDim.x + threadIdx.x;
    if (p >= B * n) return;
    unsigned pk = packed[p];
    if (!(pk & 0x80000000u)) return;
    int bb = p / n;
    float z = zbuf[p];
    float inv = 1.0f / z;
    float dlo = dminb[bb], dhi = dmaxb[bb];
    int dq = (int)((inv - dlo) / (dhi - dlo) * (float)(NQ - 1));  // trunc, matches astype(int32)
    int h = *hp, w = *wp;
    int x = (int)(pk & 0xFFFu);
    int y = (int)((pk >> 12) & 0xFFFu);
    packed[p] = pk | ((unsigned)dq << 24);
    size_t idx = (((size_t)bb * NQ + dq) * h + y) * (size_t)w + x;
    atomicMax(&winner[idx], (unsigned)p + 1u);
}

// ---------------- K3: per-pixel composite key = min over bin winners of (z_bits<<32 | bin) ----------------
__global__ void k_pixwin(const float* __restrict__ zbuf, const unsigned* __restrict__ packed,
                         const unsigned* __restrict__ winner,
                         const int* __restrict__ hp, const int* __restrict__ wp,
                         int B, int n, unsigned long long* __restrict__ pixkey) {
    int p = blockIdx.x * blockDim.x + threadIdx.x;
    if (p >= B * n) return;
    unsigned pk = packed[p];
    if (!(pk & 0x80000000u)) return;
    int bb = p / n;
    int h = *hp, w = *wp;
    int x = (int)(pk & 0xFFFu);
    int y = (int)((pk >> 12) & 0xFFFu);
    int dq = (int)((pk >> 24) & 0x3Fu);
    size_t idx = (((size_t)bb * NQ + dq) * h + y) * (size_t)w + x;
    if (winner[idx] != (unsigned)p + 1u) return;
    unsigned long long key = ((unsigned long long)__float_as_uint(zbuf[p]) << 32) | (unsigned long long)dq;
    atomicMin(&pixkey[(size_t)bb * h * w + (size_t)y * w + x], key);
}

// ---------------- K4: winning point writes depth/conf/rgb at vertically-flipped pixel ----------------
__global__ void k_resolve(const float* __restrict__ pp, const float* __restrict__ conf,
                          const float* __restrict__ zbuf, const unsigned* __restrict__ packed,
                          const unsigned* __restrict__ winner, const unsigned long long* __restrict__ pixkey,
                          const int* __restrict__ hp, const int* __restrict__ wp,
                          int B, int n, float* __restrict__ out, int pixTot) {
    int p = blockIdx.x * blockDim.x + threadIdx.x;
    if (p >= B * n) return;
    unsigned pk = packed[p];
    if (!(pk & 0x80000000u)) return;
    int bb = p / n;
    int i = p - bb * n;
    int h = *hp, w = *wp;
    int x = (int)(pk & 0xFFFu);
    int y = (int)((pk >> 12) & 0xFFFu);
    int dq = (int)((pk >> 24) & 0x3Fu);
    size_t idx = (((size_t)bb * NQ + dq) * h + y) * (size_t)w + x;
    if (winner[idx] != (unsigned)p + 1u) return;
    float z = zbuf[p];
    unsigned long long key = ((unsigned long long)__float_as_uint(z) << 32) | (unsigned long long)dq;
    size_t pix = (size_t)bb * h * w + (size_t)y * w + x;
    if (pixkey[pix] != key) return;
    int fy = h - 1 - y;   // torch.flip over h
    size_t o = (size_t)bb * h * w + (size_t)fy * w + x;
    out[o] = z;
    out[(size_t)pixTot + o] = conf[p];
    #pragma unroll
    for (int c = 0; c < 3; ++c)
        out[2 * (size_t)pixTot + (((size_t)bb * 3 + c) * h + fy) * w + x] =
            pp[((size_t)bb * 7 + 4 + c) * n + i];
}

// ---------------- K5: one hole-fill iteration (oriented-filter test + 3x3 maxpool at fill pixels) ----------------
__global__ void k_fill(const float* __restrict__ in, float* __restrict__ out,
                       const float* __restrict__ filt,
                       const int* __restrict__ hp, const int* __restrict__ wp, int B) {
    __shared__ float sf[72];
    if (threadIdx.x < 72) sf[threadIdx.x] = filt[threadIdx.x];
    __syncthreads();
    int h = *hp, w = *wp;
    int pixTot = B * h * w;
    int q = blockIdx.x * blockDim.x + threadIdx.x;
    if (q >= pixTot) return;
    int bb = q / (h * w);
    int rem = q - bb * h * w;
    int i = rem / w;
    int j = rem - i * w;

    const float* dI = in + (size_t)bb * h * w;
    const float* cI = in + (size_t)pixTot + (size_t)bb * h * w;
    const float* rI = in + 2 * (size_t)pixTot;

    float d[9];
    bool vb[9];
    #pragma unroll
    for (int t = 0; t < 9; ++t) {
        int di = i + t / 3 - 1, dj = j + t % 3 - 1;
        bool v = (di >= 0) && (di < h) && (dj >= 0) && (dj < w);
        vb[t] = v;
        d[t] = v ? dI[(size_t)di * w + dj] : 0.0f;   // zero padding for convs
    }
    float dc = d[4];
    float s = 0.0f;
    #pragma unroll
    for (int t = 0; t < 9; ++t) s += d[t];
    bool tofill = (s > 0.0f) && (dc <= 0.0f);

    float outd = dc;
    float outc = cI[(size_t)i * w + j];
    float outr[3];
    #pragma unroll
    for (int c = 0; c < 3; ++c)
        outr[c] = rI[(((size_t)bb * 3 + c) * h + i) * w + j];

    bool fill = false;
    if (tofill) {
        float prod = 1.0f;
        #pragma unroll
        for (int k = 0; k < 8; ++k) {
            float o = 0.0f;
            #pragma unroll
            for (int t = 0; t < 9; ++t) o += sf[k * 9 + t] * d[t];
            prod *= o;
        }
        fill = fabsf(prod) > 1e-10f;
    }
    if (fill) {
        float m = -INFINITY;
        #pragma unroll
        for (int t = 0; t < 9; ++t) if (vb[t]) m = fmaxf(m, d[t]);
        outd = m;
        m = -INFINITY;
        #pragma unroll
        for (int t = 0; t < 9; ++t) {
            if (vb[t]) {
                int di = i + t / 3 - 1, dj = j + t % 3 - 1;
                m = fmaxf(m, cI[(size_t)di * w + dj]);
            }
        }
        outc = m;
        #pragma unroll
        for (int c = 0; c < 3; ++c) {
            m = -INFINITY;
            #pragma unroll
            for (int t = 0; t < 9; ++t) {
                if (vb[t]) {
                    int di = i + t / 3 - 1, dj = j + t % 3 - 1;
                    m = fmaxf(m, rI[(((size_t)bb * 3 + c) * h + di) * w + dj]);
                }
            }
            outr[c] = m;
        }
    }
    size_t o0 = (size_t)bb * h * w + (size_t)i * w + j;
    out[o0] = outd;
    out[(size_t)pixTot + o0] = outc;
    #pragma unroll
    for (int c = 0; c < 3; ++c)
        out[2 * (size_t)pixTot + (((size_t)bb * 3 + c) * h + i) * w + j] = outr[c];
}

extern "C" void kernel_launch(void* const* d_in, const int* in_sizes, int n_in,
                              void* d_out, int out_size, void* d_ws, size_t ws_size,
                              hipStream_t stream) {
    const float* pp   = (const float*)d_in[0];
    const float* conf = (const float*)d_in[1];
    const float* pose = (const float*)d_in[2];
    const float* Km   = (const float*)d_in[3];
    const float* filt = (const float*)d_in[4];
    const int*   hp   = (const int*)d_in[5];
    const int*   wp   = (const int*)d_in[6];

    int B = in_sizes[2] / 16;          // pose is [B,4,4]
    int n = in_sizes[1] / B;           // conf is [B,n]
    size_t pix = (size_t)out_size / 5; // B*h*w  (out = depth + conf + 3*rgb)
    size_t npts = (size_t)B * n;

    char* ws = (char*)d_ws;
    size_t off = 0;
    unsigned* winner = (unsigned*)(ws + off);             off += (size_t)NQ * pix * 4;
    unsigned long long* pixkey = (unsigned long long*)(ws + off); off += pix * 8;
    float* zbuf = (float*)(ws + off);                     off += npts * 4;
    unsigned* packed = (unsigned*)(ws + off);             off += npts * 4;
    float* dminb = (float*)(ws + off);                    off += (size_t)B * 4;
    float* dmaxb = (float*)(ws + off);                    off += (size_t)B * 4;
    float* fieldA = (float*)(ws + off);                   off += (size_t)out_size * 4;

    float* out = (float*)d_out;

    hipMemsetAsync(winner, 0,    (size_t)NQ * pix * 4, stream);
    hipMemsetAsync(pixkey, 0xFF, pix * 8, stream);               // UINT64_MAX
    hipMemsetAsync(dminb,  0x7F, (size_t)B * 4, stream);         // 0x7F7F7F7F ~ 3.4e38 > any candidate
    hipMemsetAsync(dmaxb,  0x00, (size_t)B * 4, stream);         // 0.0 < any candidate
    hipMemsetAsync(out,    0,    (size_t)out_size * 4, stream);  // empty pixels -> 0

    const int bs = 256;
    int nptsI = (int)npts;
    k_project<<<(n + bs - 1) / bs, bs, 0, stream>>>(pp, conf, pose, Km, hp, wp, B, n,
                                                    zbuf, packed, (unsigned*)dminb, (unsigned*)dmaxb);
    k_binwin <<<(nptsI + bs - 1) / bs, bs, 0, stream>>>(zbuf, packed, dminb, dmaxb, hp, wp, B, n, winner);
    k_pixwin <<<(nptsI + bs - 1) / bs, bs, 0, stream>>>(zbuf, packed, winner, hp, wp, B, n, pixkey);
    k_resolve<<<(nptsI + bs - 1) / bs, bs, 0, stream>>>(pp, conf, zbuf, packed, winner, pixkey,
                                                        hp, wp, B, n, out, (int)pix);
    int pixI = (int)pix;
    k_fill<<<(pixI + bs - 1) / bs, bs, 0, stream>>>(out, fieldA, filt, hp, wp, B);
    k_fill<<<(pixI + bs - 1) / bs, bs, 0, stream>>>(fieldA, out, filt, hp, wp, B);
}

// Round 2
// 156.322 us; speedup vs baseline: 1.6727x; 1.6727x over previous
//
#include <hip/hip_runtime.h>
#include <stdint.h>

#define NQ 64
#define ZNEAR 0.1f
#define ZFAR 1000.0f

// ---------------- wave reductions (64-lane) ----------------
__device__ __forceinline__ float wave_min_f(float v) {
    #pragma unroll
    for (int off = 1; off < 64; off <<= 1)
        v = fminf(v, __shfl_xor(v, off, 64));
    return v;
}
__device__ __forceinline__ float wave_max_f(float v) {
    #pragma unroll
    for (int off = 1; off < 64; off <<= 1)
        v = fmaxf(v, __shfl_xor(v, off, 64));
    return v;
}

// ---------------- K0: fused init (winner=0, pixkey=0xFF..F, out=0) ----------------
// winner and pixkey are contiguous in ws; out is d_out. 16B stores + scalar tail.
__global__ void k_init(unsigned* __restrict__ wbase, size_t n_w_words, size_t n_p_words,
                       unsigned* __restrict__ obase, size_t n_o_words) {
    size_t t = (size_t)blockIdx.x * blockDim.x + threadIdx.x;
    size_t stride = (size_t)gridDim.x * blockDim.x;
    size_t tot16 = (n_w_words + n_p_words) / 4;
    uint4 zz = make_uint4(0u, 0u, 0u, 0u);
    uint4 ff = make_uint4(~0u, ~0u, ~0u, ~0u);
    uint4* w16 = (uint4*)wbase;
    size_t w16n = n_w_words / 4;   // winner region is 16B-aligned count (NQ*pix words, NQ=64)
    for (size_t k = t; k < tot16; k += stride)
        w16[k] = (k < w16n) ? zz : ff;
    // scalar tail for the combined region
    size_t tail_start = tot16 * 4;
    size_t tot_words = n_w_words + n_p_words;
    for (size_t k = tail_start + t; k < tot_words; k += stride)
        wbase[k] = (k < n_w_words) ? 0u : ~0u;
    // output zeroing
    uint4* o16 = (uint4*)obase;
    size_t o16n = n_o_words / 4;
    for (size_t k = t; k < o16n; k += stride)
        o16[k] = zz;
    for (size_t k = o16n * 4 + t; k < n_o_words; k += stride)
        obase[k] = 0u;
}

// ---------------- K1: project points, store z + packed(x,y,valid), per-block min/max partials ----
// packed layout: bit31 = valid, bits[0:12) = x, bits[12:24) = y, bits[24:30) = depth bin (K2)
__global__ void k_project(const float* __restrict__ pp, const float* __restrict__ conf,
                          const float* __restrict__ pose, const float* __restrict__ Km,
                          const int* __restrict__ hp, const int* __restrict__ wp,
                          int B, int n,
                          float* __restrict__ zbuf, unsigned* __restrict__ packed,
                          float* __restrict__ pmin, float* __restrict__ pmax, int nBlk) {
    int bb = blockIdx.y;
    int i = blockIdx.x * blockDim.x + threadIdx.x;
    int h = *hp, w = *wp;
    float inv_lo = INFINITY;   // neutral for min
    float inv_hi = 0.0f;       // neutral for max
    if (i < n) {
        const float* P  = pose + (size_t)bb * 16;
        const float* km = Km   + (size_t)bb * 9;
        const float* pb = pp   + (size_t)bb * 7 * n;
        float X  = pb[0 * (size_t)n + i];
        float Y  = pb[1 * (size_t)n + i];
        float Z  = pb[2 * (size_t)n + i];
        float Wc = pb[3 * (size_t)n + i];
        float pc0 = P[0] * X + P[1] * Y + P[2]  * Z + P[3]  * Wc;
        float pc1 = P[4] * X + P[5] * Y + P[6]  * Z + P[7]  * Wc;
        float pc2 = P[8] * X + P[9] * Y + P[10] * Z + P[11] * Wc;
        float z = fabsf(pc2);
        // mirror reference op order: (pc * f) / z + c
        float xc = pc0 * km[0] / z + km[2];
        float yc = pc1 * km[4] / z + km[5];
        float xr = rintf(xc);   // round-half-even, same as jnp.round
        float yr = rintf(yc);
        float cf = conf[(size_t)bb * n + i];
        bool valid = (xr >= 0.0f) && (xr <= (float)(w - 1)) &&
                     (yr >= 0.0f) && (yr <= (float)(h - 1)) &&
                     (z >= ZNEAR) && (z <= ZFAR) && (cf > 0.0f);
        unsigned px = valid ? (unsigned)(int)xr : 0u;
        unsigned py = valid ? (unsigned)(int)yr : 0u;
        zbuf[(size_t)bb * n + i] = z;
        packed[(size_t)bb * n + i] = (valid ? 0x80000000u : 0u) | px | (py << 12);
        // reference: 1/where(oob, 1e-10, z) and 1/where(oob, 1e10, z)
        inv_lo = valid ? (1.0f / z) : (1.0f / 1e-10f);
        inv_hi = valid ? (1.0f / z) : (1.0f / 1e10f);
    }
    // block reduction -> per-block partial (NO global atomics)
    __shared__ float smin[4], smax[4];
    float wmin = wave_min_f(inv_lo);
    float wmax = wave_max_f(inv_hi);
    int lane = threadIdx.x & 63, wid = threadIdx.x >> 6;
    if (lane == 0) { smin[wid] = wmin; smax[wid] = wmax; }
    __syncthreads();
    if (threadIdx.x == 0) {
        float m0 = fminf(fminf(smin[0], smin[1]), fminf(smin[2], smin[3]));
        float m1 = fmaxf(fmaxf(smax[0], smax[1]), fmaxf(smax[2], smax[3]));
        pmin[(size_t)bb * nBlk + blockIdx.x] = m0;
        pmax[(size_t)bb * nBlk + blockIdx.x] = m1;
    }
}

// ---------------- K1b: fold per-block partials into dmin/dmax (1 block) ----------------
__global__ void k_minmax(const float* __restrict__ pmin, const float* __restrict__ pmax,
                         int B, int nBlk, float* __restrict__ dminb, float* __restrict__ dmaxb) {
    __shared__ float smin[4], smax[4];
    for (int bb = 0; bb < B; ++bb) {
        float lmin = INFINITY, lmax = 0.0f;
        for (int k = threadIdx.x; k < nBlk; k += blockDim.x) {
            lmin = fminf(lmin, pmin[(size_t)bb * nBlk + k]);
            lmax = fmaxf(lmax, pmax[(size_t)bb * nBlk + k]);
        }
        lmin = wave_min_f(lmin);
        lmax = wave_max_f(lmax);
        int lane = threadIdx.x & 63, wid = threadIdx.x >> 6;
        if (lane == 0) { smin[wid] = lmin; smax[wid] = lmax; }
        __syncthreads();
        if (threadIdx.x == 0) {
            dminb[bb] = fminf(fminf(smin[0], smin[1]), fminf(smin[2], smin[3]));
            dmaxb[bb] = fmaxf(fmaxf(smax[0], smax[1]), fmaxf(smax[2], smax[3]));
        }
        __syncthreads();
    }
}

// ---------------- K2: compute depth bin, bin winner = max point index (last-write-wins) -------
__global__ void k_binwin(const float* __restrict__ zbuf, unsigned* __restrict__ packed,
                         const float* __restrict__ dminb, const float* __restrict__ dmaxb,
                         const int* __restrict__ hp, const int* __restrict__ wp,
                         int B, int n, unsigned* __restrict__ winner) {
    int p = blockIdx.x * blockDim.x + threadIdx.x;
    if (p >= B * n) return;
    unsigned pk = packed[p];
    if (!(pk & 0x80000000u)) return;
    int bb = p / n;
    float z = zbuf[p];
    float inv = 1.0f / z;
    float dlo = dminb[bb], dhi = dmaxb[bb];
    int dq = (int)((inv - dlo) / (dhi - dlo) * (float)(NQ - 1));  // trunc, matches astype(int32)
    int h = *hp, w = *wp;
    int x = (int)(pk & 0xFFFu);
    int y = (int)((pk >> 12) & 0xFFFu);
    packed[p] = pk | ((unsigned)dq << 24);
    size_t idx = (((size_t)bb * NQ + dq) * h + y) * (size_t)w + x;
    atomicMax(&winner[idx], (unsigned)p + 1u);
}

// ---------------- K3: per-pixel composite key = min over bin winners of (z_bits<<32 | bin) ----
__global__ void k_pixwin(const float* __restrict__ zbuf, const unsigned* __restrict__ packed,
                         const unsigned* __restrict__ winner,
                         const int* __restrict__ hp, const int* __restrict__ wp,
                         int B, int n, unsigned long long* __restrict__ pixkey) {
    int p = blockIdx.x * blockDim.x + threadIdx.x;
    if (p >= B * n) return;
    unsigned pk = packed[p];
    if (!(pk & 0x80000000u)) return;
    int bb = p / n;
    int h = *hp, w = *wp;
    int x = (int)(pk & 0xFFFu);
    int y = (int)((pk >> 12) & 0xFFFu);
    int dq = (int)((pk >> 24) & 0x3Fu);
    size_t idx = (((size_t)bb * NQ + dq) * h + y) * (size_t)w + x;
    if (winner[idx] != (unsigned)p + 1u) return;
    unsigned long long key = ((unsigned long long)__float_as_uint(zbuf[p]) << 32) | (unsigned long long)dq;
    atomicMin(&pixkey[(size_t)bb * h * w + (size_t)y * w + x], key);
}

// ---------------- K4: winning point writes depth/conf/rgb at vertically-flipped pixel --------
__global__ void k_resolve(const float* __restrict__ pp, const float* __restrict__ conf,
                          const float* __restrict__ zbuf, const unsigned* __restrict__ packed,
                          const unsigned* __restrict__ winner, const unsigned long long* __restrict__ pixkey,
                          const int* __restrict__ hp, const int* __restrict__ wp,
                          int B, int n, float* __restrict__ out, int pixTot) {
    int p = blockIdx.x * blockDim.x + threadIdx.x;
    if (p >= B * n) return;
    unsigned pk = packed[p];
    if (!(pk & 0x80000000u)) return;
    int bb = p / n;
    int i = p - bb * n;
    int h = *hp, w = *wp;
    int x = (int)(pk & 0xFFFu);
    int y = (int)((pk >> 12) & 0xFFFu);
    int dq = (int)((pk >> 24) & 0x3Fu);
    size_t idx = (((size_t)bb * NQ + dq) * h + y) * (size_t)w + x;
    if (winner[idx] != (unsigned)p + 1u) return;
    float z = zbuf[p];
    unsigned long long key = ((unsigned long long)__float_as_uint(z) << 32) | (unsigned long long)dq;
    size_t pix = (size_t)bb * h * w + (size_t)y * w + x;
    if (pixkey[pix] != key) return;
    int fy = h - 1 - y;   // torch.flip over h
    size_t o = (size_t)bb * h * w + (size_t)fy * w + x;
    out[o] = z;
    out[(size_t)pixTot + o] = conf[p];
    #pragma unroll
    for (int c = 0; c < 3; ++c)
        out[2 * (size_t)pixTot + (((size_t)bb * 3 + c) * h + fy) * w + x] =
            pp[((size_t)bb * 7 + 4 + c) * n + i];
}

// ---------------- K5: one hole-fill iteration ----------------
__global__ void k_fill(const float* __restrict__ in, float* __restrict__ out,
                       const float* __restrict__ filt,
                       const int* __restrict__ hp, const int* __restrict__ wp, int B) {
    __shared__ float sf[72];
    if (threadIdx.x < 72) sf[threadIdx.x] = filt[threadIdx.x];
    __syncthreads();
    int h = *hp, w = *wp;
    int pixTot = B * h * w;
    int q = blockIdx.x * blockDim.x + threadIdx.x;
    if (q >= pixTot) return;
    int bb = q / (h * w);
    int rem = q - bb * h * w;
    int i = rem / w;
    int j = rem - i * w;

    const float* dI = in + (size_t)bb * h * w;
    const float* cI = in + (size_t)pixTot + (size_t)bb * h * w;
    const float* rI = in + 2 * (size_t)pixTot;

    float d[9];
    bool vb[9];
    #pragma unroll
    for (int t = 0; t < 9; ++t) {
        int di = i + t / 3 - 1, dj = j + t % 3 - 1;
        bool v = (di >= 0) && (di < h) && (dj >= 0) && (dj < w);
        vb[t] = v;
        d[t] = v ? dI[(size_t)di * w + dj] : 0.0f;   // zero padding for convs
    }
    float dc = d[4];
    float s = 0.0f;
    #pragma unroll
    for (int t = 0; t < 9; ++t) s += d[t];
    bool tofill = (s > 0.0f) && (dc <= 0.0f);

    float outd = dc;
    float outc = cI[(size_t)i * w + j];
    float outr[3];
    #pragma unroll
    for (int c = 0; c < 3; ++c)
        outr[c] = rI[(((size_t)bb * 3 + c) * h + i) * w + j];

    bool fill = false;
    if (tofill) {
        float prod = 1.0f;
        #pragma unroll
        for (int k = 0; k < 8; ++k) {
            float o = 0.0f;
            #pragma unroll
            for (int t = 0; t < 9; ++t) o += sf[k * 9 + t] * d[t];
            prod *= o;
        }
        fill = fabsf(prod) > 1e-10f;
    }
    if (fill) {
        float m = -INFINITY;
        #pragma unroll
        for (int t = 0; t < 9; ++t) if (vb[t]) m = fmaxf(m, d[t]);
        outd = m;
        m = -INFINITY;
        #pragma unroll
        for (int t = 0; t < 9; ++t) {
            if (vb[t]) {
                int di = i + t / 3 - 1, dj = j + t % 3 - 1;
                m = fmaxf(m, cI[(size_t)di * w + dj]);
            }
        }
        outc = m;
        #pragma unroll
        for (int c = 0; c < 3; ++c) {
            m = -INFINITY;
            #pragma unroll
            for (int t = 0; t < 9; ++t) {
                if (vb[t]) {
                    int di = i + t / 3 - 1, dj = j + t % 3 - 1;
                    m = fmaxf(m, rI[(((size_t)bb * 3 + c) * h + di) * w + dj]);
                }
            }
            outr[c] = m;
        }
    }
    size_t o0 = (size_t)bb * h * w + (size_t)i * w + j;
    out[o0] = outd;
    out[(size_t)pixTot + o0] = outc;
    #pragma unroll
    for (int c = 0; c < 3; ++c)
        out[2 * (size_t)pixTot + (((size_t)bb * 3 + c) * h + i) * w + j] = outr[c];
}

static inline size_t align16(size_t x) { return (x + 15) & ~(size_t)15; }

extern "C" void kernel_launch(void* const* d_in, const int* in_sizes, int n_in,
                              void* d_out, int out_size, void* d_ws, size_t ws_size,
                              hipStream_t stream) {
    const float* pp   = (const float*)d_in[0];
    const float* conf = (const float*)d_in[1];
    const float* pose = (const float*)d_in[2];
    const float* Km   = (const float*)d_in[3];
    const float* filt = (const float*)d_in[4];
    const int*   hp   = (const int*)d_in[5];
    const int*   wp   = (const int*)d_in[6];

    int B = in_sizes[2] / 16;          // pose is [B,4,4]
    int n = in_sizes[1] / B;           // conf is [B,n]
    size_t pix = (size_t)out_size / 5; // B*h*w  (out = depth + conf + 3*rgb)
    size_t npts = (size_t)B * n;

    const int bs = 256;
    int nBlk = (n + bs - 1) / bs;

    char* ws = (char*)d_ws;
    size_t off = 0;
    unsigned* winner = (unsigned*)(ws + off);             off = align16(off + (size_t)NQ * pix * 4);
    unsigned long long* pixkey = (unsigned long long*)(ws + off); off = align16(off + pix * 8);
    float* zbuf = (float*)(ws + off);                     off = align16(off + npts * 4);
    unsigned* packed = (unsigned*)(ws + off);             off = align16(off + npts * 4);
    float* pminb = (float*)(ws + off);                    off = align16(off + (size_t)B * nBlk * 4);
    float* pmaxb = (float*)(ws + off);                    off = align16(off + (size_t)B * nBlk * 4);
    float* dminb = (float*)(ws + off);                    off = align16(off + (size_t)B * 4);
    float* dmaxb = (float*)(ws + off);                    off = align16(off + (size_t)B * 4);
    float* fieldA = (float*)(ws + off);                   off = align16(off + (size_t)out_size * 4);

    float* out = (float*)d_out;

    // NOTE: winner and pixkey must be contiguous for k_init's combined region.
    size_t n_w_words = (size_t)NQ * pix;           // winner dwords (value 0)
    size_t n_p_words = pix * 2;                    // pixkey dwords (value 0xFFFFFFFF)
    size_t n_o_words = (size_t)out_size;           // out dwords (value 0)

    k_init<<<1280, bs, 0, stream>>>(winner, n_w_words, n_p_words, (unsigned*)out, n_o_words);

    dim3 gproj(nBlk, B);
    k_project<<<gproj, bs, 0, stream>>>(pp, conf, pose, Km, hp, wp, B, n,
                                        zbuf, packed, pminb, pmaxb, nBlk);
    k_minmax<<<1, bs, 0, stream>>>(pminb, pmaxb, B, nBlk, dminb, dmaxb);

    int nptsI = (int)npts;
    k_binwin <<<(nptsI + bs - 1) / bs, bs, 0, stream>>>(zbuf, packed, dminb, dmaxb, hp, wp, B, n, winner);
    k_pixwin <<<(nptsI + bs - 1) / bs, bs, 0, stream>>>(zbuf, packed, winner, hp, wp, B, n, pixkey);
    k_resolve<<<(nptsI + bs - 1) / bs, bs, 0, stream>>>(pp, conf, zbuf, packed, winner, pixkey,
                                                        hp, wp, B, n, out, (int)pix);
    int pixI = (int)pix;
    k_fill<<<(pixI + bs - 1) / bs, bs, 0, stream>>>(out, fieldA, filt, hp, wp, B);
    k_fill<<<(pixI + bs - 1) / bs, bs, 0, stream>>>(fieldA, out, filt, hp, wp, B);
}

// Round 3
// 112.560 us; speedup vs baseline: 2.3230x; 1.3888x over previous
//
#include <hip/hip_runtime.h>
#include <stdint.h>

#define NQ 64
#define ZNEAR 0.1f
#define ZFAR 1000.0f
#define FT 16   // fill tile

// ---------------- wave reductions (64-lane) ----------------
__device__ __forceinline__ float wave_min_f(float v) {
    #pragma unroll
    for (int off = 1; off < 64; off <<= 1)
        v = fminf(v, __shfl_xor(v, off, 64));
    return v;
}
__device__ __forceinline__ float wave_max_f(float v) {
    #pragma unroll
    for (int off = 1; off < 64; off <<= 1)
        v = fmaxf(v, __shfl_xor(v, off, 64));
    return v;
}

// ---------------- K1: project points, store z + packed(x,y,valid), per-block min/max partials ----
// packed layout: bit31 = valid, bits[0:12) = x, bits[12:24) = y
__global__ void k_project(const float* __restrict__ pp, const float* __restrict__ conf,
                          const float* __restrict__ pose, const float* __restrict__ Km,
                          const int* __restrict__ hp, const int* __restrict__ wp,
                          int B, int n,
                          float* __restrict__ zbuf, unsigned* __restrict__ packed,
                          float* __restrict__ pmin, float* __restrict__ pmax, int nBlk) {
    int bb = blockIdx.y;
    int i = blockIdx.x * blockDim.x + threadIdx.x;
    int h = *hp, w = *wp;
    float inv_lo = INFINITY;   // neutral for min
    float inv_hi = 0.0f;       // neutral for max
    if (i < n) {
        const float* P  = pose + (size_t)bb * 16;
        const float* km = Km   + (size_t)bb * 9;
        const float* pb = pp   + (size_t)bb * 7 * n;
        float X  = pb[0 * (size_t)n + i];
        float Y  = pb[1 * (size_t)n + i];
        float Z  = pb[2 * (size_t)n + i];
        float Wc = pb[3 * (size_t)n + i];
        float pc0 = P[0] * X + P[1] * Y + P[2]  * Z + P[3]  * Wc;
        float pc1 = P[4] * X + P[5] * Y + P[6]  * Z + P[7]  * Wc;
        float pc2 = P[8] * X + P[9] * Y + P[10] * Z + P[11] * Wc;
        float z = fabsf(pc2);
        // mirror reference op order: (pc * f) / z + c
        float xc = pc0 * km[0] / z + km[2];
        float yc = pc1 * km[4] / z + km[5];
        float xr = rintf(xc);   // round-half-even, same as jnp.round
        float yr = rintf(yc);
        float cf = conf[(size_t)bb * n + i];
        bool valid = (xr >= 0.0f) && (xr <= (float)(w - 1)) &&
                     (yr >= 0.0f) && (yr <= (float)(h - 1)) &&
                     (z >= ZNEAR) && (z <= ZFAR) && (cf > 0.0f);
        unsigned px = valid ? (unsigned)(int)xr : 0u;
        unsigned py = valid ? (unsigned)(int)yr : 0u;
        zbuf[(size_t)bb * n + i] = z;
        packed[(size_t)bb * n + i] = (valid ? 0x80000000u : 0u) | px | (py << 12);
        inv_lo = valid ? (1.0f / z) : (1.0f / 1e-10f);
        inv_hi = valid ? (1.0f / z) : (1.0f / 1e10f);
    }
    __shared__ float smin[4], smax[4];
    float wmin = wave_min_f(inv_lo);
    float wmax = wave_max_f(inv_hi);
    int lane = threadIdx.x & 63, wid = threadIdx.x >> 6;
    if (lane == 0) { smin[wid] = wmin; smax[wid] = wmax; }
    __syncthreads();
    if (threadIdx.x == 0) {
        pmin[(size_t)bb * nBlk + blockIdx.x] = fminf(fminf(smin[0], smin[1]), fminf(smin[2], smin[3]));
        pmax[(size_t)bb * nBlk + blockIdx.x] = fmaxf(fmaxf(smax[0], smax[1]), fmaxf(smax[2], smax[3]));
    }
}

// ---------------- K1b: fold per-block partials into dmin/dmax (1 block) ----------------
__global__ void k_minmax(const float* __restrict__ pmin, const float* __restrict__ pmax,
                         int B, int nBlk, float* __restrict__ dminb, float* __restrict__ dmaxb) {
    __shared__ float smin[4], smax[4];
    for (int bb = 0; bb < B; ++bb) {
        float lmin = INFINITY, lmax = 0.0f;
        for (int k = threadIdx.x; k < nBlk; k += blockDim.x) {
            lmin = fminf(lmin, pmin[(size_t)bb * nBlk + k]);
            lmax = fmaxf(lmax, pmax[(size_t)bb * nBlk + k]);
        }
        lmin = wave_min_f(lmin);
        lmax = wave_max_f(lmax);
        int lane = threadIdx.x & 63, wid = threadIdx.x >> 6;
        if (lane == 0) { smin[wid] = lmin; smax[wid] = lmax; }
        __syncthreads();
        if (threadIdx.x == 0) {
            dminb[bb] = fminf(fminf(smin[0], smin[1]), fminf(smin[2], smin[3]));
            dmaxb[bb] = fmaxf(fmaxf(smax[0], smax[1]), fmaxf(smax[2], smax[3]));
        }
        __syncthreads();
    }
}

// ---------------- K2: single-atomic composite. key = (dq<<20)|(i+1), max == (highest bin, last idx).
// Valid because dq is monotone non-decreasing in 1/z: the argmin-over-bins of stored z is always
// the highest occupied bin, and within a bin the last-written (max index) point wins.
__global__ void k_scatter(const float* __restrict__ zbuf, const unsigned* __restrict__ packed,
                          const float* __restrict__ dminb, const float* __restrict__ dmaxb,
                          const int* __restrict__ hp, const int* __restrict__ wp,
                          int B, int n, unsigned* __restrict__ pixwin) {
    int p = blockIdx.x * blockDim.x + threadIdx.x;
    if (p >= B * n) return;
    unsigned pk = packed[p];
    if (!(pk & 0x80000000u)) return;
    int bb = p / n;
    int i = p - bb * n;
    float inv = 1.0f / zbuf[p];
    float dlo = dminb[bb], dhi = dmaxb[bb];
    int dq = (int)((inv - dlo) / (dhi - dlo) * (float)(NQ - 1));  // trunc, matches astype(int32); in [0,63]
    int h = *hp, w = *wp;
    int x = (int)(pk & 0xFFFu);
    int y = (int)((pk >> 12) & 0xFFFu);
    unsigned key = ((unsigned)dq << 20) | (unsigned)(i + 1);      // needs n < 2^20
    atomicMax(&pixwin[(size_t)bb * h * w + (size_t)y * w + x], key);
}

// ---------------- K3: per-pixel resolve, writes ALL output words (flipped) ----------------
__global__ void k_resolve(const float* __restrict__ pp, const float* __restrict__ conf,
                          const float* __restrict__ zbuf, const unsigned* __restrict__ pixwin,
                          const int* __restrict__ hp, const int* __restrict__ wp,
                          int B, int n, float* __restrict__ field, int pixTot) {
    int q = blockIdx.x * blockDim.x + threadIdx.x;
    if (q >= pixTot) return;               // pixTot = B*h*w
    int h = *hp, w = *wp;
    int hw = h * w;
    int bb = q / hw;
    int rem = q - bb * hw;
    int y = rem / w;
    int x = rem - y * w;
    unsigned key = pixwin[q];
    float dz = 0.0f, dc = 0.0f, r0 = 0.0f, r1 = 0.0f, r2 = 0.0f;
    if (key) {
        int i = (int)(key & 0xFFFFFu) - 1;
        size_t p = (size_t)bb * n + i;
        dz = zbuf[p];
        dc = conf[p];                       // valid points have conf > 0, so max(.,0) is a no-op
        r0 = pp[((size_t)bb * 7 + 4) * n + i];
        r1 = pp[((size_t)bb * 7 + 5) * n + i];
        r2 = pp[((size_t)bb * 7 + 6) * n + i];
    }
    int fy = h - 1 - y;                     // torch.flip over h
    size_t o = (size_t)bb * hw + (size_t)fy * w + x;
    field[o] = dz;
    field[(size_t)pixTot + o] = dc;
    size_t rb = 2 * (size_t)pixTot;
    field[rb + (((size_t)bb * 3 + 0) * h + fy) * w + x] = r0;
    field[rb + (((size_t)bb * 3 + 1) * h + fy) * w + x] = r1;
    field[rb + (((size_t)bb * 3 + 2) * h + fy) * w + x] = r2;
}

// ---------------- K4: BOTH hole-fill iterations, LDS-tiled (20x20 in -> 18x18 iter1 -> 16x16 out)
__global__ void k_fill2(const float* __restrict__ in, float* __restrict__ out,
                        const float* __restrict__ filt,
                        const int* __restrict__ hp, const int* __restrict__ wp,
                        int pixTot) {
    int h = *hp, w = *wp;
    int tilesX = (w + FT - 1) / FT;
    int tilesY = (h + FT - 1) / FT;
    int tile = blockIdx.x;
    if (tile >= tilesX * tilesY) return;    // block-uniform exit (grid has safety margin)
    int bb = blockIdx.y;
    int tY = tile / tilesX, tX = tile - tY * tilesX;
    int gy0 = tY * FT - 2, gx0 = tX * FT - 2;   // origin of the 20x20 load
    int hw = h * w;

    __shared__ float s_f[72];
    __shared__ float s_in[5][20][20];
    __shared__ float s_m[5][18][18];
    int tid = threadIdx.x;
    if (tid < 72) s_f[tid] = filt[tid];

    const float* base[5];
    base[0] = in + (size_t)bb * hw;                                  // depth
    base[1] = in + (size_t)pixTot + (size_t)bb * hw;                 // conf
    base[2] = in + 2 * (size_t)pixTot + ((size_t)bb * 3 + 0) * hw;   // rgb
    base[3] = in + 2 * (size_t)pixTot + ((size_t)bb * 3 + 1) * hw;
    base[4] = in + 2 * (size_t)pixTot + ((size_t)bb * 3 + 2) * hw;

    for (int idx = tid; idx < 400; idx += blockDim.x) {
        int yy = idx / 20, xx = idx - yy * 20;
        int gy = gy0 + yy, gx = gx0 + xx;
        bool v = ((unsigned)gy < (unsigned)h) && ((unsigned)gx < (unsigned)w);
        size_t g = (size_t)gy * w + gx;
        #pragma unroll
        for (int ch = 0; ch < 5; ++ch)
            s_in[ch][yy][xx] = v ? base[ch][g] : 0.0f;   // zero-pad == conv 'SAME'
    }
    __syncthreads();

    // ---- iteration 1 at 18x18 positions (s_in coords 1..18) ----
    for (int idx = tid; idx < 324; idx += blockDim.x) {
        int py = idx / 18, px = idx - py * 18;
        int sy = py + 1, sx = px + 1;
        int gy = gy0 + sy, gx = gx0 + sx;
        bool vc = ((unsigned)gy < (unsigned)h) && ((unsigned)gx < (unsigned)w);
        float d[9];
        #pragma unroll
        for (int t = 0; t < 9; ++t) d[t] = s_in[0][sy + t / 3 - 1][sx + t % 3 - 1];
        float s = 0.0f;
        #pragma unroll
        for (int t = 0; t < 9; ++t) s += d[t];
        float dc0 = d[4];
        float ov[5];
        #pragma unroll
        for (int ch = 0; ch < 5; ++ch) ov[ch] = s_in[ch][sy][sx];
        if ((s > 0.0f) && (dc0 <= 0.0f)) {
            float prod = 1.0f;
            #pragma unroll
            for (int k = 0; k < 8; ++k) {
                float o = 0.0f;
                #pragma unroll
                for (int t = 0; t < 9; ++t) o += s_f[k * 9 + t] * d[t];
                prod *= o;
            }
            if (fabsf(prod) > 1e-10f) {
                #pragma unroll
                for (int ch = 0; ch < 5; ++ch) {
                    float m = -INFINITY;
                    #pragma unroll
                    for (int t = 0; t < 9; ++t) {
                        int ny = gy + t / 3 - 1, nx = gx + t % 3 - 1;
                        if (((unsigned)ny < (unsigned)h) && ((unsigned)nx < (unsigned)w))
                            m = fmaxf(m, s_in[ch][sy + t / 3 - 1][sx + t % 3 - 1]);
                    }
                    ov[ch] = m;
                }
            }
        }
        if (!vc) { ov[0] = 0.0f; ov[1] = 0.0f; ov[2] = 0.0f; ov[3] = 0.0f; ov[4] = 0.0f; }
        #pragma unroll
        for (int ch = 0; ch < 5; ++ch) s_m[ch][py][px] = ov[ch];
    }
    __syncthreads();

    // ---- iteration 2 at own pixel (16x16) ----
    int ly = tid >> 4, lx = tid & 15;
    int gy = tY * FT + ly, gx = tX * FT + lx;
    if (((unsigned)gy < (unsigned)h) && ((unsigned)gx < (unsigned)w)) {
        int sy = ly + 1, sx = lx + 1;   // coords in s_m
        float d[9];
        #pragma unroll
        for (int t = 0; t < 9; ++t) d[t] = s_m[0][sy + t / 3 - 1][sx + t % 3 - 1];
        float s = 0.0f;
        #pragma unroll
        for (int t = 0; t < 9; ++t) s += d[t];
        float dc0 = d[4];
        float ov[5];
        #pragma unroll
        for (int ch = 0; ch < 5; ++ch) ov[ch] = s_m[ch][sy][sx];
        if ((s > 0.0f) && (dc0 <= 0.0f)) {
            float prod = 1.0f;
            #pragma unroll
            for (int k = 0; k < 8; ++k) {
                float o = 0.0f;
                #pragma unroll
                for (int t = 0; t < 9; ++t) o += s_f[k * 9 + t] * d[t];
                prod *= o;
            }
            if (fabsf(prod) > 1e-10f) {
                #pragma unroll
                for (int ch = 0; ch < 5; ++ch) {
                    float m = -INFINITY;
                    #pragma unroll
                    for (int t = 0; t < 9; ++t) {
                        int ny = gy + t / 3 - 1, nx = gx + t % 3 - 1;
                        if (((unsigned)ny < (unsigned)h) && ((unsigned)nx < (unsigned)w))
                            m = fmaxf(m, s_m[ch][sy + t / 3 - 1][sx + t % 3 - 1]);
                    }
                    ov[ch] = m;
                }
            }
        }
        size_t g = (size_t)gy * w + gx;
        out[(size_t)bb * hw + g] = ov[0];
        out[(size_t)pixTot + (size_t)bb * hw + g] = ov[1];
        size_t rb = 2 * (size_t)pixTot;
        out[rb + (((size_t)bb * 3 + 0) * hw) + g] = ov[2];
        out[rb + (((size_t)bb * 3 + 1) * hw) + g] = ov[3];
        out[rb + (((size_t)bb * 3 + 2) * hw) + g] = ov[4];
    }
}

static inline size_t align16(size_t x) { return (x + 15) & ~(size_t)15; }

extern "C" void kernel_launch(void* const* d_in, const int* in_sizes, int n_in,
                              void* d_out, int out_size, void* d_ws, size_t ws_size,
                              hipStream_t stream) {
    const float* pp   = (const float*)d_in[0];
    const float* conf = (const float*)d_in[1];
    const float* pose = (const float*)d_in[2];
    const float* Km   = (const float*)d_in[3];
    const float* filt = (const float*)d_in[4];
    const int*   hp   = (const int*)d_in[5];
    const int*   wp   = (const int*)d_in[6];

    int B = in_sizes[2] / 16;          // pose is [B,4,4]
    int n = in_sizes[1] / B;           // conf is [B,n]
    size_t pix = (size_t)out_size / 5; // B*h*w  (out = depth + conf + 3*rgb)
    size_t npts = (size_t)B * n;
    size_t hw = pix / B;               // h*w (host doesn't know h,w separately)

    const int bs = 256;
    int nBlk = (n + bs - 1) / bs;

    char* ws = (char*)d_ws;
    size_t off = 0;
    unsigned* pixwin = (unsigned*)(ws + off);  off = align16(off + pix * 4);
    float* zbuf   = (float*)(ws + off);        off = align16(off + npts * 4);
    unsigned* packed = (unsigned*)(ws + off);  off = align16(off + npts * 4);
    float* pminb  = (float*)(ws + off);        off = align16(off + (size_t)B * nBlk * 4);
    float* pmaxb  = (float*)(ws + off);        off = align16(off + (size_t)B * nBlk * 4);
    float* dminb  = (float*)(ws + off);        off = align16(off + (size_t)B * 4);
    float* dmaxb  = (float*)(ws + off);        off = align16(off + (size_t)B * 4);
    float* field  = (float*)(ws + off);        off = align16(off + (size_t)out_size * 4);

    float* out = (float*)d_out;

    hipMemsetAsync(pixwin, 0, pix * 4, stream);

    dim3 gproj(nBlk, B);
    k_project<<<gproj, bs, 0, stream>>>(pp, conf, pose, Km, hp, wp, B, n,
                                        zbuf, packed, pminb, pmaxb, nBlk);
    k_minmax<<<1, bs, 0, stream>>>(pminb, pmaxb, B, nBlk, dminb, dmaxb);

    int nptsI = (int)npts;
    k_scatter<<<(nptsI + bs - 1) / bs, bs, 0, stream>>>(zbuf, packed, dminb, dmaxb,
                                                        hp, wp, B, n, pixwin);
    int pixI = (int)pix;
    k_resolve<<<(pixI + bs - 1) / bs, bs, 0, stream>>>(pp, conf, zbuf, pixwin, hp, wp,
                                                       B, n, field, pixI);

    // tile-count upper bound for unknown (h,w) split of hw: (h/16+1)(w/16+1) <= hw/256 + hw/16 + 2
    size_t tileBound = hw / (FT * FT) + hw / FT + 2;
    dim3 gfill((unsigned)tileBound, B);
    k_fill2<<<gfill, bs, 0, stream>>>(field, out, filt, hp, wp, pixI);
}

// Round 4
// 104.719 us; speedup vs baseline: 2.4969x; 1.0749x over previous
//
#include <hip/hip_runtime.h>
#include <stdint.h>

#define NQ 64
#define ZNEAR 0.1f
#define ZFAR 1000.0f
#define FT 16   // fill tile

// ---------------- wave reductions (64-lane) ----------------
__device__ __forceinline__ float wave_min_f(float v) {
    #pragma unroll
    for (int off = 1; off < 64; off <<= 1)
        v = fminf(v, __shfl_xor(v, off, 64));
    return v;
}
__device__ __forceinline__ float wave_max_f(float v) {
    #pragma unroll
    for (int off = 1; off < 64; off <<= 1)
        v = fmaxf(v, __shfl_xor(v, off, 64));
    return v;
}

// ---------------- K1: project + pack + per-block min/max partials + pixwin zero + cr4 ----------
// packed layout: bit31 = valid, bits[0:12) = x, bits[12:24) = y
// cr4[p] = (conf, r, g, b) -> single-line winner gather in k_resfill.
__global__ void k_project(const float* __restrict__ pp, const float* __restrict__ conf,
                          const float* __restrict__ pose, const float* __restrict__ Km,
                          const int* __restrict__ hp, const int* __restrict__ wp,
                          int B, int n,
                          float* __restrict__ zbuf, unsigned* __restrict__ packed,
                          float4* __restrict__ cr4,
                          float* __restrict__ pmin, float* __restrict__ pmax, int nBlk,
                          unsigned* __restrict__ pixwin, int pixTot) {
    int bb = blockIdx.y;
    int i = blockIdx.x * blockDim.x + threadIdx.x;
    // fused pixwin zeroing (grid covers B*n >= pixTot threads)
    size_t ztid = ((size_t)blockIdx.y * gridDim.x + blockIdx.x) * blockDim.x + threadIdx.x;
    if (ztid < (size_t)pixTot) pixwin[ztid] = 0u;

    int h = *hp, w = *wp;
    float inv_lo = INFINITY;   // neutral for min
    float inv_hi = 0.0f;       // neutral for max
    if (i < n) {
        const float* P  = pose + (size_t)bb * 16;
        const float* km = Km   + (size_t)bb * 9;
        const float* pb = pp   + (size_t)bb * 7 * n;
        float X  = pb[0 * (size_t)n + i];
        float Y  = pb[1 * (size_t)n + i];
        float Z  = pb[2 * (size_t)n + i];
        float Wc = pb[3 * (size_t)n + i];
        float pc0 = P[0] * X + P[1] * Y + P[2]  * Z + P[3]  * Wc;
        float pc1 = P[4] * X + P[5] * Y + P[6]  * Z + P[7]  * Wc;
        float pc2 = P[8] * X + P[9] * Y + P[10] * Z + P[11] * Wc;
        float z = fabsf(pc2);
        // mirror reference op order: (pc * f) / z + c
        float xc = pc0 * km[0] / z + km[2];
        float yc = pc1 * km[4] / z + km[5];
        float xr = rintf(xc);   // round-half-even, same as jnp.round
        float yr = rintf(yc);
        float cf = conf[(size_t)bb * n + i];
        bool valid = (xr >= 0.0f) && (xr <= (float)(w - 1)) &&
                     (yr >= 0.0f) && (yr <= (float)(h - 1)) &&
                     (z >= ZNEAR) && (z <= ZFAR) && (cf > 0.0f);
        unsigned px = valid ? (unsigned)(int)xr : 0u;
        unsigned py = valid ? (unsigned)(int)yr : 0u;
        size_t p = (size_t)bb * n + i;
        zbuf[p] = z;
        packed[p] = (valid ? 0x80000000u : 0u) | px | (py << 12);
        cr4[p] = make_float4(cf, pb[4 * (size_t)n + i], pb[5 * (size_t)n + i], pb[6 * (size_t)n + i]);
        inv_lo = valid ? (1.0f / z) : (1.0f / 1e-10f);
        inv_hi = valid ? (1.0f / z) : (1.0f / 1e10f);
    }
    __shared__ float smin[4], smax[4];
    float wmin = wave_min_f(inv_lo);
    float wmax = wave_max_f(inv_hi);
    int lane = threadIdx.x & 63, wid = threadIdx.x >> 6;
    if (lane == 0) { smin[wid] = wmin; smax[wid] = wmax; }
    __syncthreads();
    if (threadIdx.x == 0) {
        pmin[(size_t)bb * nBlk + blockIdx.x] = fminf(fminf(smin[0], smin[1]), fminf(smin[2], smin[3]));
        pmax[(size_t)bb * nBlk + blockIdx.x] = fmaxf(fmaxf(smax[0], smax[1]), fmaxf(smax[2], smax[3]));
    }
}

// ---------------- K2: inline minmax fold + single-atomic composite ----------------
// key = (dq<<20)|(i+1); max == (highest bin, last index). Valid because dq is monotone
// non-decreasing in 1/z (sub/div/mul/trunc all monotone), so argmin-over-bins of stored z
// is the highest occupied bin and its stored z is the max-index point's z.
__global__ void k_scatter(const float* __restrict__ zbuf, const unsigned* __restrict__ packed,
                          const float* __restrict__ pminb, const float* __restrict__ pmaxb, int nBlk,
                          const int* __restrict__ hp, const int* __restrict__ wp,
                          int B, int n, unsigned* __restrict__ pixwin) {
    __shared__ float smin[4], smax[4];
    __shared__ float sdlo[8], sdhi[8];   // B <= 8
    // redundant per-block fold of the per-block partials (coalesced, ~nBlk*B reads)
    for (int bb = 0; bb < B; ++bb) {
        float lmin = INFINITY, lmax = 0.0f;
        for (int k = threadIdx.x; k < nBlk; k += blockDim.x) {
            lmin = fminf(lmin, pminb[(size_t)bb * nBlk + k]);
            lmax = fmaxf(lmax, pmaxb[(size_t)bb * nBlk + k]);
        }
        lmin = wave_min_f(lmin);
        lmax = wave_max_f(lmax);
        int lane = threadIdx.x & 63, wid = threadIdx.x >> 6;
        if (lane == 0) { smin[wid] = lmin; smax[wid] = lmax; }
        __syncthreads();
        if (threadIdx.x == 0) {
            sdlo[bb] = fminf(fminf(smin[0], smin[1]), fminf(smin[2], smin[3]));
            sdhi[bb] = fmaxf(fmaxf(smax[0], smax[1]), fmaxf(smax[2], smax[3]));
        }
        __syncthreads();
    }
    int p = blockIdx.x * blockDim.x + threadIdx.x;
    if (p >= B * n) return;
    unsigned pk = packed[p];
    if (!(pk & 0x80000000u)) return;
    int bb = p / n;
    int i = p - bb * n;
    float inv = 1.0f / zbuf[p];
    float dlo = sdlo[bb], dhi = sdhi[bb];
    int dq = (int)((inv - dlo) / (dhi - dlo) * (float)(NQ - 1));  // trunc, matches astype(int32)
    int h = *hp, w = *wp;
    int x = (int)(pk & 0xFFFu);
    int y = (int)((pk >> 12) & 0xFFFu);
    unsigned key = ((unsigned)dq << 20) | (unsigned)(i + 1);      // needs n < 2^20
    atomicMax(&pixwin[(size_t)bb * h * w + (size_t)y * w + x], key);
}

// ---------------- K3: fused resolve + BOTH hole-fill iterations ----------------
// Halo load resolves winners directly from pixwin at the flipped row (h-1-gy):
// 20x20 resolved halo -> iter1 at 18x18 -> iter2 at 16x16 -> store.
__global__ void k_resfill(const float* __restrict__ zbuf, const float4* __restrict__ cr4,
                          const unsigned* __restrict__ pixwin,
                          const float* __restrict__ filt,
                          const int* __restrict__ hp, const int* __restrict__ wp,
                          int B, int n, float* __restrict__ out, int pixTot) {
    int h = *hp, w = *wp;
    int tilesX = (w + FT - 1) / FT;
    int tilesY = (h + FT - 1) / FT;
    int tile = blockIdx.x;
    if (tile >= tilesX * tilesY) return;    // block-uniform exit (grid has safety margin)
    int bb = blockIdx.y;
    int tY = tile / tilesX, tX = tile - tY * tilesX;
    int gy0 = tY * FT - 2, gx0 = tX * FT - 2;   // origin of the 20x20 halo
    int hw = h * w;

    __shared__ float s_f[72];
    __shared__ float s_in[5][20][20];
    __shared__ float s_m[5][18][18];
    int tid = threadIdx.x;
    if (tid < 72) s_f[tid] = filt[tid];

    for (int idx = tid; idx < 400; idx += blockDim.x) {
        int yy = idx / 20, xx = idx - yy * 20;
        int gy = gy0 + yy, gx = gx0 + xx;
        float v0 = 0.0f, v1 = 0.0f, v2 = 0.0f, v3 = 0.0f, v4 = 0.0f;
        if (((unsigned)gy < (unsigned)h) && ((unsigned)gx < (unsigned)w)) {
            int ys = h - 1 - gy;            // flipped source row
            unsigned key = pixwin[(size_t)bb * hw + (size_t)ys * w + gx];
            if (key) {
                int i = (int)(key & 0xFFFFFu) - 1;
                size_t p = (size_t)bb * n + i;
                v0 = zbuf[p];               // z (>0); conf>0 for winners so max(.,0) is a no-op
                float4 cr = cr4[p];
                v1 = cr.x; v2 = cr.y; v3 = cr.z; v4 = cr.w;
            }
        }
        s_in[0][yy][xx] = v0;   // zero-pad outside == conv 'SAME'
        s_in[1][yy][xx] = v1;
        s_in[2][yy][xx] = v2;
        s_in[3][yy][xx] = v3;
        s_in[4][yy][xx] = v4;
    }
    __syncthreads();

    // ---- iteration 1 at 18x18 positions (s_in coords 1..18) ----
    for (int idx = tid; idx < 324; idx += blockDim.x) {
        int py = idx / 18, px = idx - py * 18;
        int sy = py + 1, sx = px + 1;
        int gy = gy0 + sy, gx = gx0 + sx;
        bool vc = ((unsigned)gy < (unsigned)h) && ((unsigned)gx < (unsigned)w);
        float d[9];
        #pragma unroll
        for (int t = 0; t < 9; ++t) d[t] = s_in[0][sy + t / 3 - 1][sx + t % 3 - 1];
        float s = 0.0f;
        #pragma unroll
        for (int t = 0; t < 9; ++t) s += d[t];
        float dc0 = d[4];
        float ov[5];
        #pragma unroll
        for (int ch = 0; ch < 5; ++ch) ov[ch] = s_in[ch][sy][sx];
        if ((s > 0.0f) && (dc0 <= 0.0f)) {
            float prod = 1.0f;
            #pragma unroll
            for (int k = 0; k < 8; ++k) {
                float o = 0.0f;
                #pragma unroll
                for (int t = 0; t < 9; ++t) o += s_f[k * 9 + t] * d[t];
                prod *= o;
            }
            if (fabsf(prod) > 1e-10f) {
                #pragma unroll
                for (int ch = 0; ch < 5; ++ch) {
                    float m = -INFINITY;
                    #pragma unroll
                    for (int t = 0; t < 9; ++t) {
                        int ny = gy + t / 3 - 1, nx = gx + t % 3 - 1;
                        if (((unsigned)ny < (unsigned)h) && ((unsigned)nx < (unsigned)w))
                            m = fmaxf(m, s_in[ch][sy + t / 3 - 1][sx + t % 3 - 1]);
                    }
                    ov[ch] = m;
                }
            }
        }
        if (!vc) { ov[0] = 0.0f; ov[1] = 0.0f; ov[2] = 0.0f; ov[3] = 0.0f; ov[4] = 0.0f; }
        #pragma unroll
        for (int ch = 0; ch < 5; ++ch) s_m[ch][py][px] = ov[ch];
    }
    __syncthreads();

    // ---- iteration 2 at own pixel (16x16) ----
    int ly = tid >> 4, lx = tid & 15;
    int gy = tY * FT + ly, gx = tX * FT + lx;
    if (((unsigned)gy < (unsigned)h) && ((unsigned)gx < (unsigned)w)) {
        int sy = ly + 1, sx = lx + 1;   // coords in s_m
        float d[9];
        #pragma unroll
        for (int t = 0; t < 9; ++t) d[t] = s_m[0][sy + t / 3 - 1][sx + t % 3 - 1];
        float s = 0.0f;
        #pragma unroll
        for (int t = 0; t < 9; ++t) s += d[t];
        float dc0 = d[4];
        float ov[5];
        #pragma unroll
        for (int ch = 0; ch < 5; ++ch) ov[ch] = s_m[ch][sy][sx];
        if ((s > 0.0f) && (dc0 <= 0.0f)) {
            float prod = 1.0f;
            #pragma unroll
            for (int k = 0; k < 8; ++k) {
                float o = 0.0f;
                #pragma unroll
                for (int t = 0; t < 9; ++t) o += s_f[k * 9 + t] * d[t];
                prod *= o;
            }
            if (fabsf(prod) > 1e-10f) {
                #pragma unroll
                for (int ch = 0; ch < 5; ++ch) {
                    float m = -INFINITY;
                    #pragma unroll
                    for (int t = 0; t < 9; ++t) {
                        int ny = gy + t / 3 - 1, nx = gx + t % 3 - 1;
                        if (((unsigned)ny < (unsigned)h) && ((unsigned)nx < (unsigned)w))
                            m = fmaxf(m, s_m[ch][sy + t / 3 - 1][sx + t % 3 - 1]);
                    }
                    ov[ch] = m;
                }
            }
        }
        size_t g = (size_t)gy * w + gx;
        out[(size_t)bb * hw + g] = ov[0];
        out[(size_t)pixTot + (size_t)bb * hw + g] = ov[1];
        size_t rb = 2 * (size_t)pixTot;
        out[rb + (((size_t)bb * 3 + 0) * hw) + g] = ov[2];
        out[rb + (((size_t)bb * 3 + 1) * hw) + g] = ov[3];
        out[rb + (((size_t)bb * 3 + 2) * hw) + g] = ov[4];
    }
}

static inline size_t align16(size_t x) { return (x + 15) & ~(size_t)15; }

extern "C" void kernel_launch(void* const* d_in, const int* in_sizes, int n_in,
                              void* d_out, int out_size, void* d_ws, size_t ws_size,
                              hipStream_t stream) {
    const float* pp   = (const float*)d_in[0];
    const float* conf = (const float*)d_in[1];
    const float* pose = (const float*)d_in[2];
    const float* Km   = (const float*)d_in[3];
    const float* filt = (const float*)d_in[4];
    const int*   hp   = (const int*)d_in[5];
    const int*   wp   = (const int*)d_in[6];

    int B = in_sizes[2] / 16;          // pose is [B,4,4]
    int n = in_sizes[1] / B;           // conf is [B,n]
    size_t pix = (size_t)out_size / 5; // B*h*w  (out = depth + conf + 3*rgb)
    size_t npts = (size_t)B * n;
    size_t hw = pix / B;               // h*w (host doesn't know h,w separately)

    const int bs = 256;
    int nBlk = (n + bs - 1) / bs;

    char* ws = (char*)d_ws;
    size_t off = 0;
    unsigned* pixwin = (unsigned*)(ws + off);  off = align16(off + pix * 4);
    float* zbuf   = (float*)(ws + off);        off = align16(off + npts * 4);
    unsigned* packed = (unsigned*)(ws + off);  off = align16(off + npts * 4);
    float4* cr4   = (float4*)(ws + off);       off = align16(off + npts * 16);
    float* pminb  = (float*)(ws + off);        off = align16(off + (size_t)B * nBlk * 4);
    float* pmaxb  = (float*)(ws + off);        off = align16(off + (size_t)B * nBlk * 4);

    float* out = (float*)d_out;
    int pixI = (int)pix;

    dim3 gproj(nBlk, B);
    k_project<<<gproj, bs, 0, stream>>>(pp, conf, pose, Km, hp, wp, B, n,
                                        zbuf, packed, cr4, pminb, pmaxb, nBlk,
                                        pixwin, pixI);

    int nptsI = (int)npts;
    k_scatter<<<(nptsI + bs - 1) / bs, bs, 0, stream>>>(zbuf, packed, pminb, pmaxb, nBlk,
                                                        hp, wp, B, n, pixwin);

    // tile-count upper bound for unknown (h,w) split of hw: (h/16+1)(w/16+1) <= hw/256 + hw/16 + 2
    size_t tileBound = hw / (FT * FT) + hw / FT + 2;
    dim3 gfill((unsigned)tileBound, B);
    k_resfill<<<gfill, bs, 0, stream>>>(zbuf, cr4, pixwin, filt, hp, wp, B, n, out, pixI);
}